// Round 1
// baseline (73.850 us; speedup 1.0000x reference)
//
#include <hip/hip_runtime.h>

// Ewald real-space sum, N=4096, aperiodic path.
// s_j = sum_i q_i * erf(d_ij/sqrt(2)) / (d_ij + 1e-6)   (diagonal = 0)
// field_j = s_j/(2pi) + 2*SELF_C*q_j
// pot     = sum_j q_j*s_j/(4pi) + SELF_C*sum_j q_j^2
// out[0] = pot, out[1..N] = field

#define NPART 4096
#define JBLK 256
#define ICHUNK 64
#define NCHUNK (NPART / ICHUNK)

// Abramowitz-Stegun 7.1.26 erf approximation, x >= 0, |err| <= 1.5e-7.
// Diagonal (x==0) is masked explicitly by the caller, so the ~1e-9 residual
// at 0 never gets divided by eps.
__device__ __forceinline__ float erf_pos(float x) {
    float t = __builtin_amdgcn_rcpf(fmaf(0.3275911f, x, 1.0f));
    float poly = fmaf(fmaf(fmaf(fmaf(1.061405429f, t, -1.453152027f),
                                t, 1.421413741f),
                           t, -0.284496736f),
                      t, 0.254829592f) * t;
    float e = __expf(-x * x);
    return fmaf(-poly, e, 1.0f);
}

__global__ __launch_bounds__(JBLK) void ewald_pairs(
        const float* __restrict__ pos,
        const float* __restrict__ q,
        float* __restrict__ s) {
    __shared__ float4 sp[ICHUNK];  // x,y,z,q of the i-chunk

    const int tid = threadIdx.x;
    const int j = blockIdx.x * JBLK + tid;     // this thread's column
    const int i0 = blockIdx.y * ICHUNK;        // this block's i-chunk

    if (tid < ICHUNK) {
        const int i = i0 + tid;
        sp[tid] = make_float4(pos[3 * i], pos[3 * i + 1], pos[3 * i + 2], q[i]);
    }

    const float px = pos[3 * j];
    const float py = pos[3 * j + 1];
    const float pz = pos[3 * j + 2];

    __syncthreads();

    float acc = 0.0f;
#pragma unroll 8
    for (int k = 0; k < ICHUNK; ++k) {
        float4 p = sp[k];  // broadcast read: all lanes same address, conflict-free
        float dx = p.x - px;
        float dy = p.y - py;
        float dz = p.z - pz;
        float d2 = fmaf(dx, dx, fmaf(dy, dy, dz * dz));
        float d = __builtin_amdgcn_sqrtf(d2);
        float x = d * 0.7071067811865475f;     // d / (sigma*sqrt(2)), sigma=1
        float erfv = erf_pos(x);
        float w = erfv * __builtin_amdgcn_rcpf(d + 1e-6f);
        w = ((i0 + k) == j) ? 0.0f : w;        // diagonal exactly 0 (matches ref)
        acc = fmaf(p.w, w, acc);               // += q_i * w_ij
    }

    atomicAdd(&s[j], acc);  // 64 consecutive addresses per wave; NCHUNK-way contention
}

__global__ __launch_bounds__(1024) void ewald_finalize(
        const float* __restrict__ q,
        const float* __restrict__ s,
        float* __restrict__ out) {
    const float INV2PI = 0.15915494309189535f;
    const float INV4PI = 0.07957747154594767f;
    const float SELFC  = 0.06349363593424097f;  // 1/(2pi)^1.5, sigma=1

    float pot = 0.0f;
    for (int j = threadIdx.x; j < NPART; j += 1024) {
        float sj = s[j];
        float qj = q[j];
        out[1 + j] = fmaf(sj, INV2PI, qj * (2.0f * SELFC));
        pot = fmaf(qj * sj, INV4PI, pot);
        pot = fmaf(qj * qj, SELFC, pot);
    }

    // block reduction: wave shuffle then LDS across 16 waves
#pragma unroll
    for (int off = 32; off > 0; off >>= 1) pot += __shfl_down(pot, off);

    __shared__ float red[16];
    const int wid = threadIdx.x >> 6;
    if ((threadIdx.x & 63) == 0) red[wid] = pot;
    __syncthreads();
    if (threadIdx.x == 0) {
        float tot = 0.0f;
#pragma unroll
        for (int w = 0; w < 16; ++w) tot += red[w];
        out[0] = tot;
    }
}

extern "C" void kernel_launch(void* const* d_in, const int* in_sizes, int n_in,
                              void* d_out, int out_size, void* d_ws, size_t ws_size,
                              hipStream_t stream) {
    const float* pos = (const float*)d_in[0];  // [N,3] f32
    const float* q   = (const float*)d_in[1];  // [N,1] f32
    float* out = (float*)d_out;                // [N+1] f32
    float* s   = (float*)d_ws;                 // N partial sums

    // ws is re-poisoned to 0xAA before every launch — must zero each call.
    hipMemsetAsync(s, 0, NPART * sizeof(float), stream);

    dim3 grid(NPART / JBLK, NCHUNK);
    hipLaunchKernelGGL(ewald_pairs, grid, dim3(JBLK), 0, stream, pos, q, s);
    hipLaunchKernelGGL(ewald_finalize, dim3(1), dim3(1024), 0, stream, q, s, out);
}

// Round 3
// 72.035 us; speedup vs baseline: 1.0252x; 1.0252x over previous
//
#include <hip/hip_runtime.h>

// Ewald real-space sum, N=4096, aperiodic path.
// s_j  = sum_i q_i * erf(d_ij/sqrt(2)) / (d_ij + 1e-6)   (diagonal = 0)
// field_j = s_j/(2pi) + 2*SELF_C*q_j
// pot     = sum_j q_j*s_j/(4pi) + SELF_C*sum_j q_j^2
// out[0] = pot, out[1..N] = field
//
// ws layout: float partial[NCHUNK][NPART]  (64*4096 floats, 1 MB)
//            float potblk[NCHUNK*NJT]      (1024 floats) after it
// No memset needed: all ws slots are unconditionally written by ewald_pairs.

#define NPART 4096
#define JBLK 256
#define ICHUNK 64
#define NCHUNK (NPART / ICHUNK)   // 64
#define NJT (NPART / JBLK)        // 16

__global__ __launch_bounds__(JBLK) void ewald_pairs(
        const float* __restrict__ pos,
        const float* __restrict__ q,
        float* __restrict__ partial,
        float* __restrict__ potblk) {
    __shared__ float4 sp[ICHUNK];  // x,y,z,q of the i-chunk
    __shared__ float red[4];

    const int tid = threadIdx.x;
    const int j = blockIdx.x * JBLK + tid;     // this thread's column
    const int i0 = blockIdx.y * ICHUNK;        // this block's i-chunk

    if (tid < ICHUNK) {
        const int i = i0 + tid;
        sp[tid] = make_float4(pos[3 * i], pos[3 * i + 1], pos[3 * i + 2], q[i]);
    }

    const float px = pos[3 * j];
    const float py = pos[3 * j + 1];
    const float pz = pos[3 * j + 2];
    const float qj = q[j];

    __syncthreads();

    float acc = 0.0f;
#pragma unroll 8
    for (int k = 0; k < ICHUNK; ++k) {
        float4 p = sp[k];  // broadcast read: all lanes same address, conflict-free
        float dx = p.x - px;
        float dy = p.y - py;
        float dz = p.z - pz;
        float d2 = fmaf(dx, dx, fmaf(dy, dy, dz * dz));
        float r  = __builtin_amdgcn_rsqf(d2);      // 1/d (inf/NaN on diagonal, masked)
        float d  = d2 * r;                          // d
        float inv = r * fmaf(-1e-6f, r, 1.0f);      // ~= 1/(d+1e-6), err O(eps^2/d^2)
        // A&S 7.1.26: t = 1/(1 + p*x), x = d/sqrt(2); p*1/sqrt(2) = 0.23165390651
        float t  = __builtin_amdgcn_rcpf(fmaf(0.23165390651f, d, 1.0f));
        float e  = __expf(-0.5f * d2);              // exp(-x^2) with x^2 = d2/2
        float poly = fmaf(fmaf(fmaf(fmaf(1.061405429f, t, -1.453152027f),
                                    t, 1.421413741f),
                               t, -0.284496736f),
                          t, 0.254829592f) * t;
        float w = fmaf(-poly, e, 1.0f) * inv;       // erf(x) * 1/(d+eps)
        w = ((i0 + k) == j) ? 0.0f : w;             // diagonal exactly 0 (matches ref)
        acc = fmaf(p.w, w, acc);                    // += q_i * w_ij
    }

    partial[blockIdx.y * NPART + j] = acc;          // coalesced, no atomics

    // block-reduce q_j * acc  ->  potblk (one value per block)
    float pj = qj * acc;
#pragma unroll
    for (int off = 32; off > 0; off >>= 1) pj += __shfl_down(pj, off);
    if ((tid & 63) == 0) red[tid >> 6] = pj;
    __syncthreads();
    if (tid == 0)
        potblk[blockIdx.y * NJT + blockIdx.x] = red[0] + red[1] + red[2] + red[3];
}

__global__ __launch_bounds__(256) void ewald_finalize(
        const float* __restrict__ q,
        const float* __restrict__ partial,
        const float* __restrict__ potblk,
        float* __restrict__ out) {
    const float INV2PI = 0.15915494309189535f;
    const float INV4PI = 0.07957747154594767f;
    const float SELFC  = 0.06349363593424097f;  // 1/(2pi)^1.5, sigma=1

    const int tid = threadIdx.x;

    if (blockIdx.x < NJT) {
        // field: sum the 64 chunk-partials for this j (coalesced per chunk)
        const int j = blockIdx.x * 256 + tid;
        float s = 0.0f;
#pragma unroll 8
        for (int c = 0; c < NCHUNK; ++c) s += partial[c * NPART + j];
        out[1 + j] = fmaf(s, INV2PI, q[j] * (2.0f * SELFC));
    } else {
        // pot: sum 1024 pre-reduced block values + self-interaction sum(q^2)
        float p = 0.0f;
#pragma unroll
        for (int c = 0; c < 4; ++c) p += potblk[c * 256 + tid];
        p *= INV4PI;
#pragma unroll
        for (int k = 0; k < 16; ++k) {
            float qq = q[tid * 16 + k];
            p = fmaf(qq * qq, SELFC, p);
        }
#pragma unroll
        for (int off = 32; off > 0; off >>= 1) p += __shfl_down(p, off);
        __shared__ float red[4];
        if ((tid & 63) == 0) red[tid >> 6] = p;
        __syncthreads();
        if (tid == 0) out[0] = red[0] + red[1] + red[2] + red[3];
    }
}

extern "C" void kernel_launch(void* const* d_in, const int* in_sizes, int n_in,
                              void* d_out, int out_size, void* d_ws, size_t ws_size,
                              hipStream_t stream) {
    const float* pos = (const float*)d_in[0];  // [N,3] f32
    const float* q   = (const float*)d_in[1];  // [N,1] f32
    float* out = (float*)d_out;                // [N+1] f32
    float* partial = (float*)d_ws;             // [64][4096]
    float* potblk  = partial + NCHUNK * NPART; // [1024]

    dim3 grid(NPART / JBLK, NCHUNK);
    hipLaunchKernelGGL(ewald_pairs, grid, dim3(JBLK), 0, stream, pos, q, partial, potblk);
    hipLaunchKernelGGL(ewald_finalize, dim3(NJT + 1), dim3(256), 0, stream, q, partial, potblk, out);
}